// Round 7
// baseline (1437.672 us; speedup 1.0000x reference)
//
#include <hip/hip_runtime.h>
#include <stdint.h>
#include <stddef.h>

#define AS1 __attribute__((address_space(1)))
#define AS3 __attribute__((address_space(3)))

typedef short bf16x8 __attribute__((ext_vector_type(8)));
typedef float f32x4 __attribute__((ext_vector_type(4)));
typedef unsigned short u16x8 __attribute__((ext_vector_type(8)));

static constexpr int N = 4096;
static constexpr int K = 2048;
static constexpr int BM = 128;         // legacy fallback tile
static constexpr int TILES = N / BM;   // 32
static constexpr int NBLK = TILES * TILES;  // 1024 (fallback)

// round-to-nearest-even f32 -> bf16
__device__ __forceinline__ unsigned short f2bf(float f) {
  union { float f; uint32_t u; } v; v.f = f;
  return (unsigned short)((v.u + 0x7FFFu + ((v.u >> 16) & 1u)) >> 16);
}

__global__ __launch_bounds__(256) void prep_kernel(
    const float* __restrict__ X, const float* __restrict__ Y,
    float* __restrict__ x2, float* __restrict__ y2,
    unsigned short* __restrict__ Xb, unsigned short* __restrict__ Yb, int wb) {
  const int row = blockIdx.x;
  const float* src = blockIdx.y ? Y : X;
  float* nrm = blockIdx.y ? y2 : x2;
  unsigned short* dst = blockIdx.y ? Yb : Xb;
  const size_t base = (size_t)row * K + threadIdx.x * 8;
  const float4 a = *(const float4*)(src + base);
  const float4 b = *(const float4*)(src + base + 4);
  double s = (double)a.x * a.x + (double)a.y * a.y + (double)a.z * a.z +
             (double)a.w * a.w + (double)b.x * b.x + (double)b.y * b.y +
             (double)b.z * b.z + (double)b.w * b.w;
  if (wb) {
    u16x8 o;
    o[0] = f2bf(a.x); o[1] = f2bf(a.y); o[2] = f2bf(a.z); o[3] = f2bf(a.w);
    o[4] = f2bf(b.x); o[5] = f2bf(b.y); o[6] = f2bf(b.z); o[7] = f2bf(b.w);
    *(u16x8*)(dst + base) = o;
  }
#pragma unroll
  for (int off = 32; off; off >>= 1) s += __shfl_down(s, off);
  __shared__ double red[4];
  if ((threadIdx.x & 63) == 0) red[threadIdx.x >> 6] = s;
  __syncthreads();
  if (threadIdx.x == 0) nrm[row] = (float)(red[0] + red[1] + red[2] + red[3]);
}

// -------- 256^2 engine, BK=32, 64KB LDS => 2 blocks/CU (496-job list) ------
// Jobs 0..255:   XY tile (ti=job&15 X-rows, tj=job>>4 Y-rows), w = -2
// Jobs 256..375: XX strict-upper off-diag tile (ti<tj), w = +2 (exact mirror)
// Jobs 376..495: YY strict-upper off-diag tile,          w = +2
// LDS regions (shorts): RB2(buf,O) = buf*16384 + O*8192 (16KB each; O=0:A,1:B).
// Region: 256 rows x 4 chunks of 16B (K=32); logical chunk c at slot
// (c + (r>>2)) & 3; source pre-swizzled so global_load_lds dest is linear.
// Schedule per K-tile t (buf = t&1):
//   P0: read af[8](A[buf]) + b0,b1(B[buf]); stage B(t+1)->buf^1; barrier;
//       16 MFMA (cols 0,1); vmcnt(4); barrier;
//   P1: read b2,b3(B[buf]); stage A(t+2)->buf; barrier;
//       16 MFMA (cols 2,3); vmcnt(2); barrier.
// Ledger: A(t),B(t) retired by the vmcnt(2)+barrier ending P1(t-1);
// overwrite-issue always follows the barrier after the region's last read.

#define RB2(bb, o) ((unsigned)((bb)*16384u + (o)*8192u))
#define VM4 asm volatile("s_waitcnt vmcnt(4)" ::: "memory")
#define VM2 asm volatile("s_waitcnt vmcnt(2)" ::: "memory")

#define STAGE2(O, TT, BB)                                                      \
  do {                                                                         \
    const unsigned short* _sp = (O) ? Bpan : Apan;                             \
    const unsigned int _kof = (unsigned)(TT) * 32u;                            \
    const unsigned int _lb = RB2(BB, O) + wseg;                                \
    __builtin_amdgcn_global_load_lds(                                          \
        (const AS1 unsigned int*)(_sp + ((O) ? sB0 : sA0) + _kof),             \
        (AS3 unsigned int*)(lds + _lb), 16, 0, 0);                             \
    __builtin_amdgcn_global_load_lds(                                          \
        (const AS1 unsigned int*)(_sp + ((O) ? sB1 : sA1) + _kof),             \
        (AS3 unsigned int*)(lds + _lb + 512u), 16, 0, 0);                      \
  } while (0)

#define PHASE2(NH, BB, VMW, ...)                                               \
  do {                                                                         \
    if constexpr ((NH) == 0) {                                                 \
      _Pragma("unroll") for (int _mi = 0; _mi < 8; ++_mi)                      \
          af[_mi] = *(const bf16x8*)(lds + RB2(BB, 0) + aoff[_mi]);            \
    }                                                                          \
    bf16x8 _b0 = *(const bf16x8*)(lds + RB2(BB, 1) + boff[(NH) * 2]);          \
    bf16x8 _b1 = *(const bf16x8*)(lds + RB2(BB, 1) + boff[(NH) * 2 + 1]);      \
    __VA_ARGS__;                                                               \
    __builtin_amdgcn_s_barrier();                                              \
    __builtin_amdgcn_s_setprio(1);                                             \
    _Pragma("unroll") for (int _mi = 0; _mi < 8; ++_mi) {                      \
      acc[_mi][(NH) * 2] = __builtin_amdgcn_mfma_f32_16x16x32_bf16(            \
          af[_mi], _b0, acc[_mi][(NH) * 2], 0, 0, 0);                          \
      acc[_mi][(NH) * 2 + 1] = __builtin_amdgcn_mfma_f32_16x16x32_bf16(        \
          af[_mi], _b1, acc[_mi][(NH) * 2 + 1], 0, 0, 0);                      \
    }                                                                          \
    __builtin_amdgcn_s_setprio(0);                                             \
    VMW;                                                                       \
    __builtin_amdgcn_s_barrier();                                              \
  } while (0)

#define TILE2(T, BB)                                                           \
  do {                                                                         \
    const int _tb = ((T) + 1 < 64) ? (T) + 1 : 63;                             \
    const int _ta = ((T) + 2 < 64) ? (T) + 2 : 63;                             \
    PHASE2(0, BB, VM4, STAGE2(1, _tb, 1 - (BB)));                              \
    PHASE2(1, BB, VM2, STAGE2(0, _ta, BB));                                    \
  } while (0)

__global__ __launch_bounds__(512, 4) void mmd_gemm8(
    const unsigned short* __restrict__ Xb, const unsigned short* __restrict__ Yb,
    const float* __restrict__ x2, const float* __restrict__ y2,
    double* __restrict__ partials) {
  __shared__ __align__(16) unsigned short lds[32768];  // 64 KiB

  const int bid = blockIdx.x;                       // 496 blocks
  const int logical = (bid & 7) * 62 + (bid >> 3);  // bijective XCD swizzle
  int ti, tj;
  const unsigned short *Apan, *Bpan;
  const float *rn, *cn;
  double wgt;
  if (logical < 256) {            // XY
    ti = logical & 15; tj = logical >> 4;
    Apan = Xb; Bpan = Yb; rn = x2; cn = y2; wgt = -2.0;
  } else {                        // XX/YY strict-upper off-diagonal
    const int q = logical - 256;
    const int pp = q / 120;       // 0: XX, 1: YY
    int jj = q % 120;
    int rr = 0;
    while (jj >= 15 - rr) { jj -= 15 - rr; ++rr; }
    ti = rr; tj = rr + 1 + jj;    // ti < tj
    Apan = Bpan = pp ? Yb : Xb;
    rn = cn = pp ? y2 : x2;
    wgt = 2.0;
  }
  const int i0 = ti << 8, j0 = tj << 8;

  const int tid = threadIdx.x;
  const int w = tid >> 6, l = tid & 63;
  const int wm = w >> 2, wn = w & 3;
  const int lr = l & 15, lq = l >> 4;

  // staging per-thread constants (region: 256 rows x 4 chunks of 16B)
  const int ci0 = w * 128 + l;
  const int ci1 = ci0 + 64;
  const int r0 = ci0 >> 2, r1 = ci1 >> 2;
  const int c0 = ((ci0 & 3) - (r0 >> 2)) & 3;
  const int c1 = ((ci1 & 3) - (r1 >> 2)) & 3;
  const unsigned int sA0 = (unsigned)(i0 + r0) * (unsigned)K + (unsigned)(c0 * 8);
  const unsigned int sA1 = (unsigned)(i0 + r1) * (unsigned)K + (unsigned)(c1 * 8);
  const unsigned int sB0 = (unsigned)(j0 + r0) * (unsigned)K + (unsigned)(c0 * 8);
  const unsigned int sB1 = (unsigned)(j0 + r1) * (unsigned)K + (unsigned)(c1 * 8);
  const unsigned int wseg = (unsigned)w * 1024u;

  // fragment read offsets (shorts, within a region)
  unsigned int aoff[8], boff[4];
#pragma unroll
  for (int mi = 0; mi < 8; ++mi) {
    const int r = wm * 128 + mi * 16 + lr;
    aoff[mi] = (unsigned)(r * 32 + (((lq + (r >> 2)) & 3) * 8));
  }
#pragma unroll
  for (int ni = 0; ni < 4; ++ni) {
    const int rb = wn * 64 + ni * 16 + lr;
    boff[ni] = (unsigned)(rb * 32 + (((lq + (rb >> 2)) & 3) * 8));
  }

  f32x4 acc[8][4] = {};
  bf16x8 af[8];

  // Prologue: A(0),B(0)->buf0, A(1)->buf1; retire A0,B0 (leave A1 in flight).
  STAGE2(0, 0, 0); STAGE2(1, 0, 0); STAGE2(0, 1, 1);
  VM2;
  __builtin_amdgcn_s_barrier();

#pragma unroll 1
  for (int tt = 0; tt < 64; tt += 2) {
    TILE2(tt, 0);
    TILE2(tt + 1, 1);
  }

  // Epilogue: expm1(-sqdist/D^2) Taylor ("+1" cancels in 1/1/-2 weights).
  const float ce = -1.0f / (2048.0f * 2048.0f);
  double s = 0.0;
#pragma unroll
  for (int mi = 0; mi < 8; ++mi) {
#pragma unroll
    for (int r4 = 0; r4 < 4; ++r4) {
      const float rv = rn[i0 + wm * 128 + mi * 16 + lq * 4 + r4];
#pragma unroll
      for (int ni = 0; ni < 4; ++ni) {
        const float cv = cn[j0 + wn * 64 + ni * 16 + lr];
        const float tx = ce * (rv + cv - 2.0f * acc[mi][ni][r4]);
        const float v =
            tx * (1.0f + tx * (0.5f + tx * (0.16666667f + tx * 0.041666668f)));
        s += (double)v;
      }
    }
  }
#pragma unroll
  for (int off = 32; off; off >>= 1) s += __shfl_down(s, off);
  __shared__ double red[8];
  if (l == 0) red[w] = s;
  __syncthreads();
  if (tid == 0) {
    double tot = 0.0;
#pragma unroll
    for (int i = 0; i < 8; ++i) tot += red[i];
    partials[logical] = wgt * tot;
  }
}

// ------ 128^2 cleanup: diagonal 256-tiles via quadrant symmetry (96 blocks) -
// Job: pair p x diag-tile d (0..15) x sub {d00 w1, d01 w2, d11 w1}.
__global__ __launch_bounds__(256) void mmd_sym128(
    const unsigned short* __restrict__ Xb, const unsigned short* __restrict__ Yb,
    const float* __restrict__ x2, const float* __restrict__ y2,
    double* __restrict__ partials) {
  const int bid = blockIdx.x;                       // 96 blocks
  const int logical = (bid & 7) * 12 + (bid >> 3);  // bijective XCD swizzle
  const int p = logical / 48;
  const int r2_ = logical % 48;
  const int d = r2_ / 3;
  const int sub = r2_ % 3;
  const double wgt = (sub == 1) ? 2.0 : 1.0;

  const unsigned short* Pan = p ? Yb : Xb;
  const float* nrm = p ? y2 : x2;
  const int i0 = d * 256 + ((sub == 2) ? 128 : 0);
  const int j0 = d * 256 + ((sub >= 1) ? 128 : 0);

  __shared__ __align__(16) unsigned short As[128 * 64];
  __shared__ __align__(16) unsigned short Bs[128 * 64];

  const int tid = threadIdx.x;
  const int w = tid >> 6, l = tid & 63;
  const int m_base = (w >> 1) * 64, n_base = (w & 1) * 64;
  const int lr = l & 15, lq = l >> 4;

  f32x4 acc[4][4] = {};

  for (int k0 = 0; k0 < K; k0 += 64) {
#pragma unroll
    for (int u = 0; u < 4; ++u) {
      const int seg = w * 4 + u;          // 16 segments x 64 chunks of 16B
      const int f = seg * 64 + l;
      const int row = f >> 3;
      const int scol = ((f & 7) ^ (row & 7)) * 8;  // inverse-swizzled source
      __builtin_amdgcn_global_load_lds(
          (const AS1 unsigned int*)(Pan + (size_t)(i0 + row) * K + k0 + scol),
          (AS3 unsigned int*)(As + seg * 512), 16, 0, 0);
      __builtin_amdgcn_global_load_lds(
          (const AS1 unsigned int*)(Pan + (size_t)(j0 + row) * K + k0 + scol),
          (AS3 unsigned int*)(Bs + seg * 512), 16, 0, 0);
    }
    __syncthreads();

#pragma unroll
    for (int kk = 0; kk < 64; kk += 32) {
      bf16x8 af2[4], bfr[4];
      const int ch = (kk >> 3) + lq;
#pragma unroll
      for (int mi = 0; mi < 4; ++mi) {
        const int r = m_base + mi * 16 + lr;
        af2[mi] = *(const bf16x8*)((const char*)As + r * 128 + ((ch ^ (r & 7)) * 16));
      }
#pragma unroll
      for (int ni = 0; ni < 4; ++ni) {
        const int r = n_base + ni * 16 + lr;
        bfr[ni] = *(const bf16x8*)((const char*)Bs + r * 128 + ((ch ^ (r & 7)) * 16));
      }
#pragma unroll
      for (int mi = 0; mi < 4; ++mi)
#pragma unroll
        for (int ni = 0; ni < 4; ++ni)
          acc[mi][ni] = __builtin_amdgcn_mfma_f32_16x16x32_bf16(
              af2[mi], bfr[ni], acc[mi][ni], 0, 0, 0);
    }
    __syncthreads();
  }

  const float ce = -1.0f / (2048.0f * 2048.0f);
  double s = 0.0;
#pragma unroll
  for (int mi = 0; mi < 4; ++mi) {
#pragma unroll
    for (int r4 = 0; r4 < 4; ++r4) {
      const float rv = nrm[i0 + m_base + mi * 16 + lq * 4 + r4];
#pragma unroll
      for (int ni = 0; ni < 4; ++ni) {
        const float cv = nrm[j0 + n_base + ni * 16 + lr];
        const float tx = ce * (rv + cv - 2.0f * acc[mi][ni][r4]);
        const float v =
            tx * (1.0f + tx * (0.5f + tx * (0.16666667f + tx * 0.041666668f)));
        s += (double)v;
      }
    }
  }
#pragma unroll
  for (int off = 32; off; off >>= 1) s += __shfl_down(s, off);
  __shared__ double red[4];
  if (l == 0) red[w] = s;
  __syncthreads();
  if (tid == 0)
    partials[496 + logical] = wgt * (red[0] + red[1] + red[2] + red[3]);
}

// ---------------- legacy 128^2 kernel (ws-too-small fallback, f32 inputs) ----
__global__ __launch_bounds__(256) void mmd_gemm_f32(
    const float* __restrict__ Xp, const float* __restrict__ Yp,
    const float* __restrict__ x2, const float* __restrict__ y2,
    double* __restrict__ partials) {
  const int p = blockIdx.y;
  const float* Ap = (p == 1) ? Yp : Xp;
  const float* Bp = (p == 0) ? Xp : Yp;
  const float* rn = (p == 1) ? y2 : x2;
  const float* cn = (p == 0) ? x2 : y2;
  const double wgt = (p == 2) ? -2.0 : 1.0;

  const int bx = blockIdx.x;
  const int i0 = (bx & (TILES - 1)) * BM;
  const int j0 = (bx / TILES) * BM;

  __shared__ __align__(16) unsigned short As[BM * 64];
  __shared__ __align__(16) unsigned short Bs[BM * 64];

  const int tid = threadIdx.x;
  const int w = tid >> 6, l = tid & 63;
  const int m_base = (w >> 1) * 64, n_base = (w & 1) * 64;

  f32x4 acc[4][4] = {};

  for (int k0 = 0; k0 < K; k0 += 64) {
#pragma unroll
    for (int u = 0; u < 4; ++u) {
      const int f = u * 256 + tid;
      const int row = f >> 3;
      const int cir = f & 7;
      const int dstb = row * 128 + ((cir ^ (row & 7)) * 16);
      {
        const float* g = Ap + (size_t)(i0 + row) * K + k0 + cir * 8;
        const float4 v0 = *(const float4*)g;
        const float4 v1 = *(const float4*)(g + 4);
        u16x8 o;
        o[0] = f2bf(v0.x); o[1] = f2bf(v0.y); o[2] = f2bf(v0.z); o[3] = f2bf(v0.w);
        o[4] = f2bf(v1.x); o[5] = f2bf(v1.y); o[6] = f2bf(v1.z); o[7] = f2bf(v1.w);
        *(u16x8*)((char*)As + dstb) = o;
      }
      {
        const float* g = Bp + (size_t)(j0 + row) * K + k0 + cir * 8;
        const float4 v0 = *(const float4*)g;
        const float4 v1 = *(const float4*)(g + 4);
        u16x8 o;
        o[0] = f2bf(v0.x); o[1] = f2bf(v0.y); o[2] = f2bf(v0.z); o[3] = f2bf(v0.w);
        o[4] = f2bf(v1.x); o[5] = f2bf(v1.y); o[6] = f2bf(v1.z); o[7] = f2bf(v1.w);
        *(u16x8*)((char*)Bs + dstb) = o;
      }
    }
    __syncthreads();

#pragma unroll
    for (int kk = 0; kk < 64; kk += 32) {
      bf16x8 af2[4], bfr[4];
      const int lr = l & 15;
      const int ch = (kk >> 3) + (l >> 4);
#pragma unroll
      for (int mi = 0; mi < 4; ++mi) {
        const int r = m_base + mi * 16 + lr;
        af2[mi] = *(const bf16x8*)((const char*)As + r * 128 + ((ch ^ (r & 7)) * 16));
      }
#pragma unroll
      for (int ni = 0; ni < 4; ++ni) {
        const int r = n_base + ni * 16 + lr;
        bfr[ni] = *(const bf16x8*)((const char*)Bs + r * 128 + ((ch ^ (r & 7)) * 16));
      }
#pragma unroll
      for (int mi = 0; mi < 4; ++mi)
#pragma unroll
        for (int ni = 0; ni < 4; ++ni)
          acc[mi][ni] = __builtin_amdgcn_mfma_f32_16x16x32_bf16(
              af2[mi], bfr[ni], acc[mi][ni], 0, 0, 0);
    }
    __syncthreads();
  }

  const float ce = -1.0f / (2048.0f * 2048.0f);
  double s = 0.0;
  const int lr = l & 15, lq = l >> 4;
#pragma unroll
  for (int mi = 0; mi < 4; ++mi) {
#pragma unroll
    for (int r4 = 0; r4 < 4; ++r4) {
      const float rv = rn[i0 + m_base + mi * 16 + lq * 4 + r4];
#pragma unroll
      for (int ni = 0; ni < 4; ++ni) {
        const float cv = cn[j0 + n_base + ni * 16 + lr];
        const float tx = ce * (rv + cv - 2.0f * acc[mi][ni][r4]);
        const float v =
            tx * (1.0f + tx * (0.5f + tx * (0.16666667f + tx * 0.041666668f)));
        s += (double)v;
      }
    }
  }
#pragma unroll
  for (int off = 32; off; off >>= 1) s += __shfl_down(s, off);
  __shared__ double red[4];
  if (l == 0) red[w] = s;
  __syncthreads();
  if (tid == 0) partials[p * NBLK + bx] = wgt * (red[0] + red[1] + red[2] + red[3]);
}

__global__ __launch_bounds__(256) void finalize_kernel(
    const double* __restrict__ partials, float* __restrict__ out, int n) {
  double s = 0.0;
  for (int i = threadIdx.x; i < n; i += 256) s += partials[i];
#pragma unroll
  for (int off = 32; off; off >>= 1) s += __shfl_down(s, off);
  __shared__ double red[4];
  if ((threadIdx.x & 63) == 0) red[threadIdx.x >> 6] = s;
  __syncthreads();
  if (threadIdx.x == 0)
    out[0] = (float)((red[0] + red[1] + red[2] + red[3]) *
                     (1.0 / ((double)N * (double)N)));
}

extern "C" void kernel_launch(void* const* d_in, const int* in_sizes, int n_in,
                              void* d_out, int out_size, void* d_ws,
                              size_t ws_size, hipStream_t stream) {
  const float* X = (const float*)d_in[0];
  const float* Y = (const float*)d_in[1];
  char* ws = (char*)d_ws;

  double* partials = (double*)ws;           // fast: 592 f64; fallback: 3072
  float* x2 = (float*)(ws + 24576);
  float* y2 = (float*)(ws + 24576 + 16384);
  unsigned short* Xb = (unsigned short*)(ws + 65536);
  unsigned short* Yb = Xb + (size_t)N * K;
  const size_t need_fast = (size_t)65536 + (size_t)2 * N * K * 2;
  const bool fast = ws_size >= need_fast;

  prep_kernel<<<dim3(N, 2), 256, 0, stream>>>(X, Y, x2, y2, Xb, Yb, fast ? 1 : 0);
  if (fast) {
    mmd_gemm8<<<dim3(496), dim3(512), 0, stream>>>(Xb, Yb, x2, y2, partials);
    mmd_sym128<<<dim3(96), dim3(256), 0, stream>>>(Xb, Yb, x2, y2, partials);
    finalize_kernel<<<1, 256, 0, stream>>>(partials, (float*)d_out, 592);
  } else {
    mmd_gemm_f32<<<dim3(NBLK, 3), 256, 0, stream>>>(X, Y, x2, y2, partials);
    finalize_kernel<<<1, 256, 0, stream>>>(partials, (float*)d_out, 3072);
  }
}

// Round 8
// 183.587 us; speedup vs baseline: 7.8310x; 7.8310x over previous
//
#include <hip/hip_runtime.h>
#include <stdint.h>
#include <stddef.h>

#define AS1 __attribute__((address_space(1)))
#define AS3 __attribute__((address_space(3)))

typedef short bf16x8 __attribute__((ext_vector_type(8)));
typedef float f32x4 __attribute__((ext_vector_type(4)));
typedef unsigned short u16x8 __attribute__((ext_vector_type(8)));

static constexpr int N = 4096;
static constexpr int K = 2048;
static constexpr int BM = 128;         // legacy fallback tile
static constexpr int TILES = N / BM;   // 32
static constexpr int NBLK = TILES * TILES;  // 1024 (fallback)

// round-to-nearest-even f32 -> bf16
__device__ __forceinline__ unsigned short f2bf(float f) {
  union { float f; uint32_t u; } v; v.f = f;
  return (unsigned short)((v.u + 0x7FFFu + ((v.u >> 16) & 1u)) >> 16);
}

__global__ __launch_bounds__(256) void prep_kernel(
    const float* __restrict__ X, const float* __restrict__ Y,
    float* __restrict__ x2, float* __restrict__ y2,
    unsigned short* __restrict__ Xb, unsigned short* __restrict__ Yb, int wb) {
  const int row = blockIdx.x;
  const float* src = blockIdx.y ? Y : X;
  float* nrm = blockIdx.y ? y2 : x2;
  unsigned short* dst = blockIdx.y ? Yb : Xb;
  const size_t base = (size_t)row * K + threadIdx.x * 8;
  const float4 a = *(const float4*)(src + base);
  const float4 b = *(const float4*)(src + base + 4);
  double s = (double)a.x * a.x + (double)a.y * a.y + (double)a.z * a.z +
             (double)a.w * a.w + (double)b.x * b.x + (double)b.y * b.y +
             (double)b.z * b.z + (double)b.w * b.w;
  if (wb) {
    u16x8 o;
    o[0] = f2bf(a.x); o[1] = f2bf(a.y); o[2] = f2bf(a.z); o[3] = f2bf(a.w);
    o[4] = f2bf(b.x); o[5] = f2bf(b.y); o[6] = f2bf(b.z); o[7] = f2bf(b.w);
    *(u16x8*)(dst + base) = o;
  }
#pragma unroll
  for (int off = 32; off; off >>= 1) s += __shfl_down(s, off);
  __shared__ double red[4];
  if ((threadIdx.x & 63) == 0) red[threadIdx.x >> 6] = s;
  __syncthreads();
  if (threadIdx.x == 0) nrm[row] = (float)(red[0] + red[1] + red[2] + red[3]);
}

// -------- 256^2 engine, BK=32, 64KB LDS => 2 blocks/CU (496-job list) ------
// Jobs 0..255:   XY tile (ti=job&15 X-rows, tj=job>>4 Y-rows), w = -2
// Jobs 256..375: XX strict-upper off-diag tile (ti<tj), w = +2 (exact mirror)
// Jobs 376..495: YY strict-upper off-diag tile,          w = +2
// LDS regions (shorts): RB2(buf,O) = buf*16384 + O*8192 (16KB each; O=0:A,1:B).
// Region: 256 rows x 4 chunks of 16B (K=32); logical chunk c at slot
// (c + (r>>2)) & 3; source pre-swizzled so global_load_lds dest is linear.
// Schedule per K-tile t (buf = t&1):
//   P0: read af[8](A[buf]) + b0,b1(B[buf]); stage B(t+1)->buf^1; barrier;
//       16 MFMA (cols 0,1); vmcnt(4); barrier;
//   P1: read b2,b3(B[buf]); stage A(t+2)->buf; barrier;
//       16 MFMA (cols 2,3); vmcnt(2); barrier.
// Ledger: A(t),B(t) retired by the vmcnt(2)+barrier ending P1(t-1);
// overwrite-issue always follows the barrier after the region's last read.
// NOTE: __launch_bounds__ second arg MUST stay 2 — arg=4 forced a 64-VGPR
// cap and catastrophic scratch spills (r7: 4.3 GB WRITE_SIZE, 7.9x slower).

#define RB2(bb, o) ((unsigned)((bb)*16384u + (o)*8192u))
#define VM4 asm volatile("s_waitcnt vmcnt(4)" ::: "memory")
#define VM2 asm volatile("s_waitcnt vmcnt(2)" ::: "memory")

#define STAGE2(O, TT, BB)                                                      \
  do {                                                                         \
    const unsigned short* _sp = (O) ? Bpan : Apan;                             \
    const unsigned int _kof = (unsigned)(TT) * 32u;                            \
    const unsigned int _lb = RB2(BB, O) + wseg;                                \
    __builtin_amdgcn_global_load_lds(                                          \
        (const AS1 unsigned int*)(_sp + ((O) ? sB0 : sA0) + _kof),             \
        (AS3 unsigned int*)(lds + _lb), 16, 0, 0);                             \
    __builtin_amdgcn_global_load_lds(                                          \
        (const AS1 unsigned int*)(_sp + ((O) ? sB1 : sA1) + _kof),             \
        (AS3 unsigned int*)(lds + _lb + 512u), 16, 0, 0);                      \
  } while (0)

#define PHASE2(NH, BB, VMW, ...)                                               \
  do {                                                                         \
    if constexpr ((NH) == 0) {                                                 \
      _Pragma("unroll") for (int _mi = 0; _mi < 8; ++_mi)                      \
          af[_mi] = *(const bf16x8*)(lds + RB2(BB, 0) + aoff[_mi]);            \
    }                                                                          \
    bf16x8 _b0 = *(const bf16x8*)(lds + RB2(BB, 1) + boff[(NH) * 2]);          \
    bf16x8 _b1 = *(const bf16x8*)(lds + RB2(BB, 1) + boff[(NH) * 2 + 1]);      \
    __VA_ARGS__;                                                               \
    __builtin_amdgcn_s_barrier();                                              \
    __builtin_amdgcn_s_setprio(1);                                             \
    _Pragma("unroll") for (int _mi = 0; _mi < 8; ++_mi) {                      \
      acc[_mi][(NH) * 2] = __builtin_amdgcn_mfma_f32_16x16x32_bf16(            \
          af[_mi], _b0, acc[_mi][(NH) * 2], 0, 0, 0);                          \
      acc[_mi][(NH) * 2 + 1] = __builtin_amdgcn_mfma_f32_16x16x32_bf16(        \
          af[_mi], _b1, acc[_mi][(NH) * 2 + 1], 0, 0, 0);                      \
    }                                                                          \
    __builtin_amdgcn_s_setprio(0);                                             \
    VMW;                                                                       \
    __builtin_amdgcn_s_barrier();                                              \
  } while (0)

#define TILE2(T, BB)                                                           \
  do {                                                                         \
    const int _tb = ((T) + 1 < 64) ? (T) + 1 : 63;                             \
    const int _ta = ((T) + 2 < 64) ? (T) + 2 : 63;                             \
    PHASE2(0, BB, VM4, STAGE2(1, _tb, 1 - (BB)));                              \
    PHASE2(1, BB, VM2, STAGE2(0, _ta, BB));                                    \
  } while (0)

__global__ __launch_bounds__(512, 2) void mmd_gemm8(
    const unsigned short* __restrict__ Xb, const unsigned short* __restrict__ Yb,
    const float* __restrict__ x2, const float* __restrict__ y2,
    double* __restrict__ partials) {
  __shared__ __align__(16) unsigned short lds[32768];  // 64 KiB

  const int bid = blockIdx.x;                       // 496 blocks
  const int logical = (bid & 7) * 62 + (bid >> 3);  // bijective XCD swizzle
  int ti, tj;
  const unsigned short *Apan, *Bpan;
  const float *rn, *cn;
  double wgt;
  if (logical < 256) {            // XY
    ti = logical & 15; tj = logical >> 4;
    Apan = Xb; Bpan = Yb; rn = x2; cn = y2; wgt = -2.0;
  } else {                        // XX/YY strict-upper off-diagonal
    const int q = logical - 256;
    const int pp = q / 120;       // 0: XX, 1: YY
    int jj = q % 120;
    int rr = 0;
    while (jj >= 15 - rr) { jj -= 15 - rr; ++rr; }
    ti = rr; tj = rr + 1 + jj;    // ti < tj
    Apan = Bpan = pp ? Yb : Xb;
    rn = cn = pp ? y2 : x2;
    wgt = 2.0;
  }
  const int i0 = ti << 8, j0 = tj << 8;

  const int tid = threadIdx.x;
  const int w = tid >> 6, l = tid & 63;
  const int wm = w >> 2, wn = w & 3;
  const int lr = l & 15, lq = l >> 4;

  // staging per-thread constants (region: 256 rows x 4 chunks of 16B)
  const int ci0 = w * 128 + l;
  const int ci1 = ci0 + 64;
  const int r0 = ci0 >> 2, r1 = ci1 >> 2;
  const int c0 = ((ci0 & 3) - (r0 >> 2)) & 3;
  const int c1 = ((ci1 & 3) - (r1 >> 2)) & 3;
  const unsigned int sA0 = (unsigned)(i0 + r0) * (unsigned)K + (unsigned)(c0 * 8);
  const unsigned int sA1 = (unsigned)(i0 + r1) * (unsigned)K + (unsigned)(c1 * 8);
  const unsigned int sB0 = (unsigned)(j0 + r0) * (unsigned)K + (unsigned)(c0 * 8);
  const unsigned int sB1 = (unsigned)(j0 + r1) * (unsigned)K + (unsigned)(c1 * 8);
  const unsigned int wseg = (unsigned)w * 1024u;

  // fragment read offsets (shorts, within a region)
  unsigned int aoff[8], boff[4];
#pragma unroll
  for (int mi = 0; mi < 8; ++mi) {
    const int r = wm * 128 + mi * 16 + lr;
    aoff[mi] = (unsigned)(r * 32 + (((lq + (r >> 2)) & 3) * 8));
  }
#pragma unroll
  for (int ni = 0; ni < 4; ++ni) {
    const int rb = wn * 64 + ni * 16 + lr;
    boff[ni] = (unsigned)(rb * 32 + (((lq + (rb >> 2)) & 3) * 8));
  }

  f32x4 acc[8][4] = {};
  bf16x8 af[8];

  // Prologue: A(0),B(0)->buf0, A(1)->buf1; retire A0,B0 (leave A1 in flight).
  STAGE2(0, 0, 0); STAGE2(1, 0, 0); STAGE2(0, 1, 1);
  VM2;
  __builtin_amdgcn_s_barrier();

#pragma unroll 1
  for (int tt = 0; tt < 64; tt += 2) {
    TILE2(tt, 0);
    TILE2(tt + 1, 1);
  }

  // Epilogue: expm1(-sqdist/D^2) Taylor ("+1" cancels in 1/1/-2 weights).
  const float ce = -1.0f / (2048.0f * 2048.0f);
  double s = 0.0;
#pragma unroll
  for (int mi = 0; mi < 8; ++mi) {
#pragma unroll
    for (int r4 = 0; r4 < 4; ++r4) {
      const float rv = rn[i0 + wm * 128 + mi * 16 + lq * 4 + r4];
#pragma unroll
      for (int ni = 0; ni < 4; ++ni) {
        const float cv = cn[j0 + wn * 64 + ni * 16 + lr];
        const float tx = ce * (rv + cv - 2.0f * acc[mi][ni][r4]);
        const float v =
            tx * (1.0f + tx * (0.5f + tx * (0.16666667f + tx * 0.041666668f)));
        s += (double)v;
      }
    }
  }
#pragma unroll
  for (int off = 32; off; off >>= 1) s += __shfl_down(s, off);
  __shared__ double red[8];
  if (l == 0) red[w] = s;
  __syncthreads();
  if (tid == 0) {
    double tot = 0.0;
#pragma unroll
    for (int i = 0; i < 8; ++i) tot += red[i];
    partials[logical] = wgt * tot;
  }
}

// ------ 128^2 cleanup: diagonal 256-tiles via quadrant symmetry (96 blocks) -
// Job: pair p x diag-tile d (0..15) x sub {d00 w1, d01 w2, d11 w1}.
__global__ __launch_bounds__(256) void mmd_sym128(
    const unsigned short* __restrict__ Xb, const unsigned short* __restrict__ Yb,
    const float* __restrict__ x2, const float* __restrict__ y2,
    double* __restrict__ partials) {
  const int bid = blockIdx.x;                       // 96 blocks
  const int logical = (bid & 7) * 12 + (bid >> 3);  // bijective XCD swizzle
  const int p = logical / 48;
  const int r2_ = logical % 48;
  const int d = r2_ / 3;
  const int sub = r2_ % 3;
  const double wgt = (sub == 1) ? 2.0 : 1.0;

  const unsigned short* Pan = p ? Yb : Xb;
  const float* nrm = p ? y2 : x2;
  const int i0 = d * 256 + ((sub == 2) ? 128 : 0);
  const int j0 = d * 256 + ((sub >= 1) ? 128 : 0);

  __shared__ __align__(16) unsigned short As[128 * 64];
  __shared__ __align__(16) unsigned short Bs[128 * 64];

  const int tid = threadIdx.x;
  const int w = tid >> 6, l = tid & 63;
  const int m_base = (w >> 1) * 64, n_base = (w & 1) * 64;
  const int lr = l & 15, lq = l >> 4;

  f32x4 acc[4][4] = {};

  for (int k0 = 0; k0 < K; k0 += 64) {
#pragma unroll
    for (int u = 0; u < 4; ++u) {
      const int seg = w * 4 + u;          // 16 segments x 64 chunks of 16B
      const int f = seg * 64 + l;
      const int row = f >> 3;
      const int scol = ((f & 7) ^ (row & 7)) * 8;  // inverse-swizzled source
      __builtin_amdgcn_global_load_lds(
          (const AS1 unsigned int*)(Pan + (size_t)(i0 + row) * K + k0 + scol),
          (AS3 unsigned int*)(As + seg * 512), 16, 0, 0);
      __builtin_amdgcn_global_load_lds(
          (const AS1 unsigned int*)(Pan + (size_t)(j0 + row) * K + k0 + scol),
          (AS3 unsigned int*)(Bs + seg * 512), 16, 0, 0);
    }
    __syncthreads();

#pragma unroll
    for (int kk = 0; kk < 64; kk += 32) {
      bf16x8 af2[4], bfr[4];
      const int ch = (kk >> 3) + lq;
#pragma unroll
      for (int mi = 0; mi < 4; ++mi) {
        const int r = m_base + mi * 16 + lr;
        af2[mi] = *(const bf16x8*)((const char*)As + r * 128 + ((ch ^ (r & 7)) * 16));
      }
#pragma unroll
      for (int ni = 0; ni < 4; ++ni) {
        const int r = n_base + ni * 16 + lr;
        bfr[ni] = *(const bf16x8*)((const char*)Bs + r * 128 + ((ch ^ (r & 7)) * 16));
      }
#pragma unroll
      for (int mi = 0; mi < 4; ++mi)
#pragma unroll
        for (int ni = 0; ni < 4; ++ni)
          acc[mi][ni] = __builtin_amdgcn_mfma_f32_16x16x32_bf16(
              af2[mi], bfr[ni], acc[mi][ni], 0, 0, 0);
    }
    __syncthreads();
  }

  const float ce = -1.0f / (2048.0f * 2048.0f);
  double s = 0.0;
#pragma unroll
  for (int mi = 0; mi < 4; ++mi) {
#pragma unroll
    for (int r4 = 0; r4 < 4; ++r4) {
      const float rv = nrm[i0 + m_base + mi * 16 + lq * 4 + r4];
#pragma unroll
      for (int ni = 0; ni < 4; ++ni) {
        const float cv = nrm[j0 + n_base + ni * 16 + lr];
        const float tx = ce * (rv + cv - 2.0f * acc[mi][ni][r4]);
        const float v =
            tx * (1.0f + tx * (0.5f + tx * (0.16666667f + tx * 0.041666668f)));
        s += (double)v;
      }
    }
  }
#pragma unroll
  for (int off = 32; off; off >>= 1) s += __shfl_down(s, off);
  __shared__ double red[4];
  if (l == 0) red[w] = s;
  __syncthreads();
  if (tid == 0)
    partials[496 + logical] = wgt * (red[0] + red[1] + red[2] + red[3]);
}

// ---------------- legacy 128^2 kernel (ws-too-small fallback, f32 inputs) ----
__global__ __launch_bounds__(256) void mmd_gemm_f32(
    const float* __restrict__ Xp, const float* __restrict__ Yp,
    const float* __restrict__ x2, const float* __restrict__ y2,
    double* __restrict__ partials) {
  const int p = blockIdx.y;
  const float* Ap = (p == 1) ? Yp : Xp;
  const float* Bp = (p == 0) ? Xp : Yp;
  const float* rn = (p == 1) ? y2 : x2;
  const float* cn = (p == 0) ? x2 : y2;
  const double wgt = (p == 2) ? -2.0 : 1.0;

  const int bx = blockIdx.x;
  const int i0 = (bx & (TILES - 1)) * BM;
  const int j0 = (bx / TILES) * BM;

  __shared__ __align__(16) unsigned short As[BM * 64];
  __shared__ __align__(16) unsigned short Bs[BM * 64];

  const int tid = threadIdx.x;
  const int w = tid >> 6, l = tid & 63;
  const int m_base = (w >> 1) * 64, n_base = (w & 1) * 64;

  f32x4 acc[4][4] = {};

  for (int k0 = 0; k0 < K; k0 += 64) {
#pragma unroll
    for (int u = 0; u < 4; ++u) {
      const int f = u * 256 + tid;
      const int row = f >> 3;
      const int cir = f & 7;
      const int dstb = row * 128 + ((cir ^ (row & 7)) * 16);
      {
        const float* g = Ap + (size_t)(i0 + row) * K + k0 + cir * 8;
        const float4 v0 = *(const float4*)g;
        const float4 v1 = *(const float4*)(g + 4);
        u16x8 o;
        o[0] = f2bf(v0.x); o[1] = f2bf(v0.y); o[2] = f2bf(v0.z); o[3] = f2bf(v0.w);
        o[4] = f2bf(v1.x); o[5] = f2bf(v1.y); o[6] = f2bf(v1.z); o[7] = f2bf(v1.w);
        *(u16x8*)((char*)As + dstb) = o;
      }
      {
        const float* g = Bp + (size_t)(j0 + row) * K + k0 + cir * 8;
        const float4 v0 = *(const float4*)g;
        const float4 v1 = *(const float4*)(g + 4);
        u16x8 o;
        o[0] = f2bf(v0.x); o[1] = f2bf(v0.y); o[2] = f2bf(v0.z); o[3] = f2bf(v0.w);
        o[4] = f2bf(v1.x); o[5] = f2bf(v1.y); o[6] = f2bf(v1.z); o[7] = f2bf(v1.w);
        *(u16x8*)((char*)Bs + dstb) = o;
      }
    }
    __syncthreads();

#pragma unroll
    for (int kk = 0; kk < 64; kk += 32) {
      bf16x8 af2[4], bfr[4];
      const int lr = l & 15;
      const int ch = (kk >> 3) + (l >> 4);
#pragma unroll
      for (int mi = 0; mi < 4; ++mi) {
        const int r = m_base + mi * 16 + lr;
        af2[mi] = *(const bf16x8*)((const char*)As + r * 128 + ((ch ^ (r & 7)) * 16));
      }
#pragma unroll
      for (int ni = 0; ni < 4; ++ni) {
        const int r = n_base + ni * 16 + lr;
        bfr[ni] = *(const bf16x8*)((const char*)Bs + r * 128 + ((ch ^ (r & 7)) * 16));
      }
#pragma unroll
      for (int mi = 0; mi < 4; ++mi)
#pragma unroll
        for (int ni = 0; ni < 4; ++ni)
          acc[mi][ni] = __builtin_amdgcn_mfma_f32_16x16x32_bf16(
              af2[mi], bfr[ni], acc[mi][ni], 0, 0, 0);
    }
    __syncthreads();
  }

  const float ce = -1.0f / (2048.0f * 2048.0f);
  double s = 0.0;
  const int lr = l & 15, lq = l >> 4;
#pragma unroll
  for (int mi = 0; mi < 4; ++mi) {
#pragma unroll
    for (int r4 = 0; r4 < 4; ++r4) {
      const float rv = rn[i0 + m_base + mi * 16 + lq * 4 + r4];
#pragma unroll
      for (int ni = 0; ni < 4; ++ni) {
        const float cv = cn[j0 + n_base + ni * 16 + lr];
        const float tx = ce * (rv + cv - 2.0f * acc[mi][ni][r4]);
        const float v =
            tx * (1.0f + tx * (0.5f + tx * (0.16666667f + tx * 0.041666668f)));
        s += (double)v;
      }
    }
  }
#pragma unroll
  for (int off = 32; off; off >>= 1) s += __shfl_down(s, off);
  __shared__ double red[4];
  if (l == 0) red[w] = s;
  __syncthreads();
  if (tid == 0) partials[p * NBLK + bx] = wgt * (red[0] + red[1] + red[2] + red[3]);
}

__global__ __launch_bounds__(256) void finalize_kernel(
    const double* __restrict__ partials, float* __restrict__ out, int n) {
  double s = 0.0;
  for (int i = threadIdx.x; i < n; i += 256) s += partials[i];
#pragma unroll
  for (int off = 32; off; off >>= 1) s += __shfl_down(s, off);
  __shared__ double red[4];
  if ((threadIdx.x & 63) == 0) red[threadIdx.x >> 6] = s;
  __syncthreads();
  if (threadIdx.x == 0)
    out[0] = (float)((red[0] + red[1] + red[2] + red[3]) *
                     (1.0 / ((double)N * (double)N)));
}

extern "C" void kernel_launch(void* const* d_in, const int* in_sizes, int n_in,
                              void* d_out, int out_size, void* d_ws,
                              size_t ws_size, hipStream_t stream) {
  const float* X = (const float*)d_in[0];
  const float* Y = (const float*)d_in[1];
  char* ws = (char*)d_ws;

  double* partials = (double*)ws;           // fast: 592 f64; fallback: 3072
  float* x2 = (float*)(ws + 24576);
  float* y2 = (float*)(ws + 24576 + 16384);
  unsigned short* Xb = (unsigned short*)(ws + 65536);
  unsigned short* Yb = Xb + (size_t)N * K;
  const size_t need_fast = (size_t)65536 + (size_t)2 * N * K * 2;
  const bool fast = ws_size >= need_fast;

  prep_kernel<<<dim3(N, 2), 256, 0, stream>>>(X, Y, x2, y2, Xb, Yb, fast ? 1 : 0);
  if (fast) {
    mmd_gemm8<<<dim3(496), dim3(512), 0, stream>>>(Xb, Yb, x2, y2, partials);
    mmd_sym128<<<dim3(96), dim3(256), 0, stream>>>(Xb, Yb, x2, y2, partials);
    finalize_kernel<<<1, 256, 0, stream>>>(partials, (float*)d_out, 592);
  } else {
    mmd_gemm_f32<<<dim3(NBLK, 3), 256, 0, stream>>>(X, Y, x2, y2, partials);
    finalize_kernel<<<1, 256, 0, stream>>>(partials, (float*)d_out, 3072);
  }
}

// Round 9
// 180.058 us; speedup vs baseline: 7.9845x; 1.0196x over previous
//
#include <hip/hip_runtime.h>
#include <stdint.h>
#include <stddef.h>

#define AS1 __attribute__((address_space(1)))
#define AS3 __attribute__((address_space(3)))

typedef short bf16x8 __attribute__((ext_vector_type(8)));
typedef float f32x4 __attribute__((ext_vector_type(4)));
typedef unsigned short u16x8 __attribute__((ext_vector_type(8)));

static constexpr int N = 4096;
static constexpr int K = 2048;
static constexpr int BM = 128;         // legacy fallback tile
static constexpr int TILES = N / BM;   // 32
static constexpr int NBLK = TILES * TILES;  // 1024 (fallback)

// round-to-nearest-even f32 -> bf16
__device__ __forceinline__ unsigned short f2bf(float f) {
  union { float f; uint32_t u; } v; v.f = f;
  return (unsigned short)((v.u + 0x7FFFu + ((v.u >> 16) & 1u)) >> 16);
}

__global__ __launch_bounds__(256) void prep_kernel(
    const float* __restrict__ X, const float* __restrict__ Y,
    float* __restrict__ x2, float* __restrict__ y2,
    unsigned short* __restrict__ Xb, unsigned short* __restrict__ Yb, int wb) {
  const int row = blockIdx.x;
  const float* src = blockIdx.y ? Y : X;
  float* nrm = blockIdx.y ? y2 : x2;
  unsigned short* dst = blockIdx.y ? Yb : Xb;
  const size_t base = (size_t)row * K + threadIdx.x * 8;
  const float4 a = *(const float4*)(src + base);
  const float4 b = *(const float4*)(src + base + 4);
  double s = (double)a.x * a.x + (double)a.y * a.y + (double)a.z * a.z +
             (double)a.w * a.w + (double)b.x * b.x + (double)b.y * b.y +
             (double)b.z * b.z + (double)b.w * b.w;
  if (wb) {
    u16x8 o;
    o[0] = f2bf(a.x); o[1] = f2bf(a.y); o[2] = f2bf(a.z); o[3] = f2bf(a.w);
    o[4] = f2bf(b.x); o[5] = f2bf(b.y); o[6] = f2bf(b.z); o[7] = f2bf(b.w);
    *(u16x8*)(dst + base) = o;
  }
#pragma unroll
  for (int off = 32; off; off >>= 1) s += __shfl_down(s, off);
  __shared__ double red[4];
  if ((threadIdx.x & 63) == 0) red[threadIdx.x >> 6] = s;
  __syncthreads();
  if (threadIdx.x == 0) nrm[row] = (float)(red[0] + red[1] + red[2] + red[3]);
}

// -------- 256^2 engine, BK=64, 128B-row XOR-swizzled LDS (496-job list) ----
// Jobs 0..255:   XY tile (ti=job&15 X-rows, tj=job>>4 Y-rows), w = -2
// Jobs 256..375: XX strict-upper off-diag tile (ti<tj), w = +2 (exact mirror)
// Jobs 376..495: YY strict-upper off-diag tile,          w = +2
// LDS: RB3(buf,O) = buf*32768 + O*16384 shorts; region = 256 rows x 64 K
// (128B rows, 8 chunks of 16B). Logical chunk c stored at slot c ^ (r&7)
// (r1-verified conflict-free pattern; dword = r*32 + slot*4 spans all banks,
// 2-way max aliasing = free). Source pre-swizzled; gload_lds dest linear.
// Per K-tile t (b=t&1), 4 phases (ks x nh); reads use aoff^(ks*32):
//   P1(k0,n01): af(k0)+b0,b1 | stage A(t+1)h1 -> b^1
//   P2(k0,n23): b2,b3        | stage B(t+1)h0 -> b^1
//   P3(k1,n01): af(k1)+b0,b1 | stage B(t+1)h1 -> b^1
//   P4(k1,n23): b2,b3        | stage A(t+2)h0 -> b ; vmcnt(2)
// Ledger: at end-P4(t) only A(t+2)h0 in flight => A(t+1),B(t+1) complete
// before P1(t+1). A[b] dead after P3, B[b] after P4; all stage-issues follow
// the barrier after the target region's last read (incl. clamped tail).
// NOTE: occupancy is register-bound at 2 waves/SIMD (8 waves = 1 block/CU);
// 128KB LDS costs nothing. __launch_bounds__ 2nd arg must stay 2 (r7: arg=4
// => 64-VGPR cap => 4.3GB scratch spills, 7.9x slower).

#define RB3(bb, o) ((unsigned)((bb)*32768u + (o)*16384u))
#define VM2 asm volatile("s_waitcnt vmcnt(2)" ::: "memory")
#define VM_NONE

#define STG(O, TT, BB, H)                                                      \
  do {                                                                         \
    const unsigned short* _sp = (O) ? Bpan : Apan;                             \
    const unsigned int _so =                                                   \
        ((O) ? sB : sA) + (unsigned)(H) * 262144u + (unsigned)(TT) * 64u;      \
    const unsigned int _lb = RB3(BB, O) + (unsigned)(H) * 8192u + wseg;        \
    __builtin_amdgcn_global_load_lds(                                          \
        (const AS1 unsigned int*)(_sp + _so),                                  \
        (AS3 unsigned int*)(lds + _lb), 16, 0, 0);                             \
    __builtin_amdgcn_global_load_lds(                                          \
        (const AS1 unsigned int*)(_sp + _so + 16384u),                         \
        (AS3 unsigned int*)(lds + _lb + 512u), 16, 0, 0);                      \
  } while (0)

#define PH(KS, NH, BB, VMW, ...)                                               \
  do {                                                                         \
    if constexpr ((NH) == 0) {                                                 \
      _Pragma("unroll") for (int _mi = 0; _mi < 8; ++_mi)                      \
          af[_mi] = *(const bf16x8*)(lds + RB3(BB, 0) +                        \
                                     (aoff[_mi] ^ ((KS) * 32u)));              \
    }                                                                          \
    bf16x8 _b0 = *(const bf16x8*)(lds + RB3(BB, 1) +                           \
                                  (boff[(NH) * 2] ^ ((KS) * 32u)));            \
    bf16x8 _b1 = *(const bf16x8*)(lds + RB3(BB, 1) +                           \
                                  (boff[(NH) * 2 + 1] ^ ((KS) * 32u)));        \
    __VA_ARGS__;                                                               \
    __builtin_amdgcn_s_barrier();                                              \
    __builtin_amdgcn_s_setprio(1);                                             \
    _Pragma("unroll") for (int _mi = 0; _mi < 8; ++_mi) {                      \
      acc[_mi][(NH) * 2] = __builtin_amdgcn_mfma_f32_16x16x32_bf16(            \
          af[_mi], _b0, acc[_mi][(NH) * 2], 0, 0, 0);                          \
      acc[_mi][(NH) * 2 + 1] = __builtin_amdgcn_mfma_f32_16x16x32_bf16(        \
          af[_mi], _b1, acc[_mi][(NH) * 2 + 1], 0, 0, 0);                      \
    }                                                                          \
    __builtin_amdgcn_s_setprio(0);                                             \
    VMW;                                                                       \
    __builtin_amdgcn_s_barrier();                                              \
  } while (0)

#define TILE3(T, BB)                                                           \
  do {                                                                         \
    const int _t1 = ((T) + 1 < 32) ? (T) + 1 : 31;                             \
    const int _t2 = ((T) + 2 < 32) ? (T) + 2 : 31;                             \
    PH(0, 0, BB, VM_NONE, STG(0, _t1, 1 - (BB), 1));                           \
    PH(0, 1, BB, VM_NONE, STG(1, _t1, 1 - (BB), 0));                           \
    PH(1, 0, BB, VM_NONE, STG(1, _t1, 1 - (BB), 1));                           \
    PH(1, 1, BB, VM2,     STG(0, _t2, (BB), 0));                               \
  } while (0)

__global__ __launch_bounds__(512, 2) void mmd_gemm8(
    const unsigned short* __restrict__ Xb, const unsigned short* __restrict__ Yb,
    const float* __restrict__ x2, const float* __restrict__ y2,
    double* __restrict__ partials) {
  __shared__ __align__(16) unsigned short lds[65536];  // 128 KiB

  const int bid = blockIdx.x;                       // 496 blocks
  const int logical = (bid & 7) * 62 + (bid >> 3);  // bijective XCD swizzle
  int ti, tj;
  const unsigned short *Apan, *Bpan;
  const float *rn, *cn;
  double wgt;
  if (logical < 256) {            // XY
    ti = logical & 15; tj = logical >> 4;
    Apan = Xb; Bpan = Yb; rn = x2; cn = y2; wgt = -2.0;
  } else {                        // XX/YY strict-upper off-diagonal
    const int q = logical - 256;
    const int pp = q / 120;       // 0: XX, 1: YY
    int jj = q % 120;
    int rr = 0;
    while (jj >= 15 - rr) { jj -= 15 - rr; ++rr; }
    ti = rr; tj = rr + 1 + jj;    // ti < tj
    Apan = Bpan = pp ? Yb : Xb;
    rn = cn = pp ? y2 : x2;
    wgt = 2.0;
  }
  const int i0 = ti << 8, j0 = tj << 8;

  const int tid = threadIdx.x;
  const int w = tid >> 6, l = tid & 63;
  const int wm = w >> 2, wn = w & 3;
  const int lr = l & 15, lq = l >> 4;

  // staging per-thread constants: chunk ci = h*1024 + w*128 + (l | 64-step);
  // r = ci>>3, slot = ci&7, logical c = slot ^ (r&7). (r&7) and slot are
  // invariant under ci += 64 / += 1024, so ONE base offset per operand; the
  // +64-chunk load is src +16384 elems, h=1 is +262144 elems (uniform).
  const int ci = w * 128 + l;
  const int rr0 = ci >> 3;
  const int cc0 = (ci & 7) ^ (rr0 & 7);
  const unsigned int sA = (unsigned)(i0 + rr0) * (unsigned)K + (unsigned)(cc0 * 8);
  const unsigned int sB = (unsigned)(j0 + rr0) * (unsigned)K + (unsigned)(cc0 * 8);
  const unsigned int wseg = (unsigned)w * 1024u;

  // fragment read offsets (shorts, within a 16384-short region)
  unsigned int aoff[8], boff[4];
#pragma unroll
  for (int mi = 0; mi < 8; ++mi) {
    const int r = wm * 128 + mi * 16 + lr;
    aoff[mi] = (unsigned)(r * 64 + ((lq ^ (r & 7)) * 8));
  }
#pragma unroll
  for (int ni = 0; ni < 4; ++ni) {
    const int rb = wn * 64 + ni * 16 + lr;
    boff[ni] = (unsigned)(rb * 64 + ((lq ^ (rb & 7)) * 8));
  }

  f32x4 acc[8][4] = {};
  bf16x8 af[8];

  // Prologue: A(0),B(0) full + A(1)h0 = 10 loads; retire all but A(1)h0.
  STG(0, 0, 0, 0); STG(0, 0, 0, 1); STG(1, 0, 0, 0); STG(1, 0, 0, 1);
  STG(0, 1, 1, 0);
  VM2;
  __builtin_amdgcn_s_barrier();

#pragma unroll 1
  for (int tt = 0; tt < 32; tt += 2) {
    TILE3(tt, 0);
    TILE3(tt + 1, 1);
  }

  // Epilogue: expm1(-sqdist/D^2) Taylor ("+1" cancels in 1/1/-2 weights).
  const float ce = -1.0f / (2048.0f * 2048.0f);
  double s = 0.0;
#pragma unroll
  for (int mi = 0; mi < 8; ++mi) {
#pragma unroll
    for (int r4 = 0; r4 < 4; ++r4) {
      const float rv = rn[i0 + wm * 128 + mi * 16 + lq * 4 + r4];
#pragma unroll
      for (int ni = 0; ni < 4; ++ni) {
        const float cv = cn[j0 + wn * 64 + ni * 16 + lr];
        const float tx = ce * (rv + cv - 2.0f * acc[mi][ni][r4]);
        const float v =
            tx * (1.0f + tx * (0.5f + tx * (0.16666667f + tx * 0.041666668f)));
        s += (double)v;
      }
    }
  }
#pragma unroll
  for (int off = 32; off; off >>= 1) s += __shfl_down(s, off);
  __shared__ double red[8];
  if (l == 0) red[w] = s;
  __syncthreads();
  if (tid == 0) {
    double tot = 0.0;
#pragma unroll
    for (int i = 0; i < 8; ++i) tot += red[i];
    partials[logical] = wgt * tot;
  }
}

// ------ 128^2 cleanup: diagonal 256-tiles via quadrant symmetry (96 blocks) -
// Job: pair p x diag-tile d (0..15) x sub {d00 w1, d01 w2, d11 w1}.
__global__ __launch_bounds__(256) void mmd_sym128(
    const unsigned short* __restrict__ Xb, const unsigned short* __restrict__ Yb,
    const float* __restrict__ x2, const float* __restrict__ y2,
    double* __restrict__ partials) {
  const int bid = blockIdx.x;                       // 96 blocks
  const int logical = (bid & 7) * 12 + (bid >> 3);  // bijective XCD swizzle
  const int p = logical / 48;
  const int r2_ = logical % 48;
  const int d = r2_ / 3;
  const int sub = r2_ % 3;
  const double wgt = (sub == 1) ? 2.0 : 1.0;

  const unsigned short* Pan = p ? Yb : Xb;
  const float* nrm = p ? y2 : x2;
  const int i0 = d * 256 + ((sub == 2) ? 128 : 0);
  const int j0 = d * 256 + ((sub >= 1) ? 128 : 0);

  __shared__ __align__(16) unsigned short As[128 * 64];
  __shared__ __align__(16) unsigned short Bs[128 * 64];

  const int tid = threadIdx.x;
  const int w = tid >> 6, l = tid & 63;
  const int m_base = (w >> 1) * 64, n_base = (w & 1) * 64;
  const int lr = l & 15, lq = l >> 4;

  f32x4 acc[4][4] = {};

  for (int k0 = 0; k0 < K; k0 += 64) {
#pragma unroll
    for (int u = 0; u < 4; ++u) {
      const int seg = w * 4 + u;          // 16 segments x 64 chunks of 16B
      const int f = seg * 64 + l;
      const int row = f >> 3;
      const int scol = ((f & 7) ^ (row & 7)) * 8;  // inverse-swizzled source
      __builtin_amdgcn_global_load_lds(
          (const AS1 unsigned int*)(Pan + (size_t)(i0 + row) * K + k0 + scol),
          (AS3 unsigned int*)(As + seg * 512), 16, 0, 0);
      __builtin_amdgcn_global_load_lds(
          (const AS1 unsigned int*)(Pan + (size_t)(j0 + row) * K + k0 + scol),
          (AS3 unsigned int*)(Bs + seg * 512), 16, 0, 0);
    }
    __syncthreads();

#pragma unroll
    for (int kk = 0; kk < 64; kk += 32) {
      bf16x8 af2[4], bfr[4];
      const int ch = (kk >> 3) + lq;
#pragma unroll
      for (int mi = 0; mi < 4; ++mi) {
        const int r = m_base + mi * 16 + lr;
        af2[mi] = *(const bf16x8*)((const char*)As + r * 128 + ((ch ^ (r & 7)) * 16));
      }
#pragma unroll
      for (int ni = 0; ni < 4; ++ni) {
        const int r = n_base + ni * 16 + lr;
        bfr[ni] = *(const bf16x8*)((const char*)Bs + r * 128 + ((ch ^ (r & 7)) * 16));
      }
#pragma unroll
      for (int mi = 0; mi < 4; ++mi)
#pragma unroll
        for (int ni = 0; ni < 4; ++ni)
          acc[mi][ni] = __builtin_amdgcn_mfma_f32_16x16x32_bf16(
              af2[mi], bfr[ni], acc[mi][ni], 0, 0, 0);
    }
    __syncthreads();
  }

  const float ce = -1.0f / (2048.0f * 2048.0f);
  double s = 0.0;
#pragma unroll
  for (int mi = 0; mi < 4; ++mi) {
#pragma unroll
    for (int r4 = 0; r4 < 4; ++r4) {
      const float rv = nrm[i0 + m_base + mi * 16 + lq * 4 + r4];
#pragma unroll
      for (int ni = 0; ni < 4; ++ni) {
        const float cv = nrm[j0 + n_base + ni * 16 + lr];
        const float tx = ce * (rv + cv - 2.0f * acc[mi][ni][r4]);
        const float v =
            tx * (1.0f + tx * (0.5f + tx * (0.16666667f + tx * 0.041666668f)));
        s += (double)v;
      }
    }
  }
#pragma unroll
  for (int off = 32; off; off >>= 1) s += __shfl_down(s, off);
  __shared__ double red[4];
  if (l == 0) red[w] = s;
  __syncthreads();
  if (tid == 0)
    partials[496 + logical] = wgt * (red[0] + red[1] + red[2] + red[3]);
}

// ---------------- legacy 128^2 kernel (ws-too-small fallback, f32 inputs) ----
__global__ __launch_bounds__(256) void mmd_gemm_f32(
    const float* __restrict__ Xp, const float* __restrict__ Yp,
    const float* __restrict__ x2, const float* __restrict__ y2,
    double* __restrict__ partials) {
  const int p = blockIdx.y;
  const float* Ap = (p == 1) ? Yp : Xp;
  const float* Bp = (p == 0) ? Xp : Yp;
  const float* rn = (p == 1) ? y2 : x2;
  const float* cn = (p == 0) ? x2 : y2;
  const double wgt = (p == 2) ? -2.0 : 1.0;

  const int bx = blockIdx.x;
  const int i0 = (bx & (TILES - 1)) * BM;
  const int j0 = (bx / TILES) * BM;

  __shared__ __align__(16) unsigned short As[BM * 64];
  __shared__ __align__(16) unsigned short Bs[BM * 64];

  const int tid = threadIdx.x;
  const int w = tid >> 6, l = tid & 63;
  const int m_base = (w >> 1) * 64, n_base = (w & 1) * 64;

  f32x4 acc[4][4] = {};

  for (int k0 = 0; k0 < K; k0 += 64) {
#pragma unroll
    for (int u = 0; u < 4; ++u) {
      const int f = u * 256 + tid;
      const int row = f >> 3;
      const int cir = f & 7;
      const int dstb = row * 128 + ((cir ^ (row & 7)) * 16);
      {
        const float* g = Ap + (size_t)(i0 + row) * K + k0 + cir * 8;
        const float4 v0 = *(const float4*)g;
        const float4 v1 = *(const float4*)(g + 4);
        u16x8 o;
        o[0] = f2bf(v0.x); o[1] = f2bf(v0.y); o[2] = f2bf(v0.z); o[3] = f2bf(v0.w);
        o[4] = f2bf(v1.x); o[5] = f2bf(v1.y); o[6] = f2bf(v1.z); o[7] = f2bf(v1.w);
        *(u16x8*)((char*)As + dstb) = o;
      }
      {
        const float* g = Bp + (size_t)(j0 + row) * K + k0 + cir * 8;
        const float4 v0 = *(const float4*)g;
        const float4 v1 = *(const float4*)(g + 4);
        u16x8 o;
        o[0] = f2bf(v0.x); o[1] = f2bf(v0.y); o[2] = f2bf(v0.z); o[3] = f2bf(v0.w);
        o[4] = f2bf(v1.x); o[5] = f2bf(v1.y); o[6] = f2bf(v1.z); o[7] = f2bf(v1.w);
        *(u16x8*)((char*)Bs + dstb) = o;
      }
    }
    __syncthreads();

#pragma unroll
    for (int kk = 0; kk < 64; kk += 32) {
      bf16x8 af2[4], bfr[4];
      const int lr = l & 15;
      const int ch = (kk >> 3) + (l >> 4);
#pragma unroll
      for (int mi = 0; mi < 4; ++mi) {
        const int r = m_base + mi * 16 + lr;
        af2[mi] = *(const bf16x8*)((const char*)As + r * 128 + ((ch ^ (r & 7)) * 16));
      }
#pragma unroll
      for (int ni = 0; ni < 4; ++ni) {
        const int r = n_base + ni * 16 + lr;
        bfr[ni] = *(const bf16x8*)((const char*)Bs + r * 128 + ((ch ^ (r & 7)) * 16));
      }
#pragma unroll
      for (int mi = 0; mi < 4; ++mi)
#pragma unroll
        for (int ni = 0; ni < 4; ++ni)
          acc[mi][ni] = __builtin_amdgcn_mfma_f32_16x16x32_bf16(
              af2[mi], bfr[ni], acc[mi][ni], 0, 0, 0);
    }
    __syncthreads();
  }

  const float ce = -1.0f / (2048.0f * 2048.0f);
  double s = 0.0;
  const int lr = l & 15, lq = l >> 4;
#pragma unroll
  for (int mi = 0; mi < 4; ++mi) {
#pragma unroll
    for (int r4 = 0; r4 < 4; ++r4) {
      const float rv = rn[i0 + m_base + mi * 16 + lq * 4 + r4];
#pragma unroll
      for (int ni = 0; ni < 4; ++ni) {
        const float cv = cn[j0 + n_base + ni * 16 + lr];
        const float tx = ce * (rv + cv - 2.0f * acc[mi][ni][r4]);
        const float v =
            tx * (1.0f + tx * (0.5f + tx * (0.16666667f + tx * 0.041666668f)));
        s += (double)v;
      }
    }
  }
#pragma unroll
  for (int off = 32; off; off >>= 1) s += __shfl_down(s, off);
  __shared__ double red[4];
  if (l == 0) red[w] = s;
  __syncthreads();
  if (tid == 0) partials[p * NBLK + bx] = wgt * (red[0] + red[1] + red[2] + red[3]);
}

__global__ __launch_bounds__(256) void finalize_kernel(
    const double* __restrict__ partials, float* __restrict__ out, int n) {
  double s = 0.0;
  for (int i = threadIdx.x; i < n; i += 256) s += partials[i];
#pragma unroll
  for (int off = 32; off; off >>= 1) s += __shfl_down(s, off);
  __shared__ double red[4];
  if ((threadIdx.x & 63) == 0) red[threadIdx.x >> 6] = s;
  __syncthreads();
  if (threadIdx.x == 0)
    out[0] = (float)((red[0] + red[1] + red[2] + red[3]) *
                     (1.0 / ((double)N * (double)N)));
}

extern "C" void kernel_launch(void* const* d_in, const int* in_sizes, int n_in,
                              void* d_out, int out_size, void* d_ws,
                              size_t ws_size, hipStream_t stream) {
  const float* X = (const float*)d_in[0];
  const float* Y = (const float*)d_in[1];
  char* ws = (char*)d_ws;

  double* partials = (double*)ws;           // fast: 592 f64; fallback: 3072
  float* x2 = (float*)(ws + 24576);
  float* y2 = (float*)(ws + 24576 + 16384);
  unsigned short* Xb = (unsigned short*)(ws + 65536);
  unsigned short* Yb = Xb + (size_t)N * K;
  const size_t need_fast = (size_t)65536 + (size_t)2 * N * K * 2;
  const bool fast = ws_size >= need_fast;

  prep_kernel<<<dim3(N, 2), 256, 0, stream>>>(X, Y, x2, y2, Xb, Yb, fast ? 1 : 0);
  if (fast) {
    mmd_gemm8<<<dim3(496), dim3(512), 0, stream>>>(Xb, Yb, x2, y2, partials);
    mmd_sym128<<<dim3(96), dim3(256), 0, stream>>>(Xb, Yb, x2, y2, partials);
    finalize_kernel<<<1, 256, 0, stream>>>(partials, (float*)d_out, 592);
  } else {
    mmd_gemm_f32<<<dim3(NBLK, 3), 256, 0, stream>>>(X, Y, x2, y2, partials);
    finalize_kernel<<<1, 256, 0, stream>>>(partials, (float*)d_out, 3072);
  }
}